// Round 7
// baseline (120.368 us; speedup 1.0000x reference)
//
#include <hip/hip_runtime.h>

// x: [B=16, T=16384, C=64] fp32. bp_sos/lp_sos: [2,6] fp32 rows (b0,b1,b2,a0,a1,a2; a0==1).
#define B_LEN 16
#define T_LEN 16384
#define C_LEN 64
#define CHUNK 64    // outputs per thread; amp 2.0x (warm 64); 1024 blocks = 16 waves/CU
#define WARM  64    // zero-state warmup; transient ~0.83^64 ~ 7e-6 (empirically safe: absmax 0.0156)

// R12: store-decoupled pipeline. Evidence R3/R9/R10: every phase carries a
// ~2300-2500cy stall that TLP doesn't hide, regardless of wave count or VMEM
// width -- matches a store-drain round trip. Mechanism: vmcnt retires IN ISSUE
// ORDER and loads/stores SHARE vmcnt on gfx9-lineage; any load issued after a
// nontemporal store (acks at memory, not L2) cannot decrement vmcnt until that
// store completes, so every consume-wait inherits the write drain. R9's
// within-phase reorder only removed same-phase coupling (-2us); phase-k stores
// still gate phase-k+1 loads.
// Fix: NO stores in the steady-state loop. Outputs accumulate in a 32-reg Y
// buffer; stores issue in two batches (after sample 32, and at kernel end).
// Loads consumed in the loop never sit behind stores in the vmcnt FIFO (the
// only post-store loads are issued ~8 phases before consumption -> covered).
// Y reuse across halves is safe+cheap: store data-reads retire via expcnt
// (read at issue), not vmcnt -- compiler inserts the expcnt wait.
// Geometry back to R3: 1 ch/thread scalar dword, 256thr = 4 batches x 64 ch,
// grid (256,4) = 1024 blocks = 16 waves/CU. VGPR est ~90 -> 4 waves/SIMD ok.
// step() arithmetic order unchanged -> bit-identical output (absmax 0.015625).
__global__ __launch_bounds__(256, 4) void iir_defer_kernel(
    const float* __restrict__ x,
    const float* __restrict__ bp,
    const float* __restrict__ lp,
    float* __restrict__ out)
{
    const int c     = threadIdx.x & 63;        // channel within batch
    const int bsub  = threadIdx.x >> 6;        // 0..3
    const int b     = blockIdx.y * 4 + bsub;   // batch 0..15
    const int chunk = blockIdx.x;              // 0..T/CHUNK-1

    // Uniform coefficients -> scalar (SGPR) loads. a's negated so updates are pure FMA.
    const float b10 = bp[0], b11 = bp[1], b12 = bp[2],  a11 = -bp[4],  a12 = -bp[5];
    const float b20 = bp[6], b21 = bp[7], b22 = bp[8],  a21 = -bp[10], a22 = -bp[11];
    const float b30 = lp[0], b31 = lp[1], b32 = lp[2],  a31 = -lp[4],  a32 = -lp[5];
    const float b40 = lp[6], b41 = lp[7], b42 = lp[8],  a41 = -lp[10], a42 = -lp[11];

    const int t_out0 = chunk * CHUNK;
    const int warm   = (t_out0 < WARM) ? t_out0 : WARM;  // 0 (chunk 0) or 64, block-uniform
    const int t0     = t_out0 - warm;

    // DF2T state: 2 per section
    float s11 = 0.f, s12 = 0.f;
    float s21 = 0.f, s22 = 0.f;
    float s31 = 0.f, s32 = 0.f;
    float s41 = 0.f, s42 = 0.f;

    const float* __restrict__ lq = x   + ((size_t)b * T_LEN + t0)     * C_LEN + c;
    float*       __restrict__ po = out + ((size_t)b * T_LEN + t_out0) * C_LEN + c;

    auto step = [&](float xn) -> float {
        // section 1 (bandpass)
        float y1 = fmaf(b10, xn, s11);
        s11 = fmaf(b11, xn, fmaf(a11, y1, s12));
        s12 = fmaf(b12, xn, a12 * y1);
        // section 2 (bandpass)
        float y2 = fmaf(b20, y1, s21);
        s21 = fmaf(b21, y1, fmaf(a21, y2, s22));
        s22 = fmaf(b22, y1, a22 * y2);
        // squaring nonlinearity
        float v = y2 * y2;
        // section 3 (lowpass)
        float y3 = fmaf(b30, v, s31);
        s31 = fmaf(b31, v, fmaf(a31, y3, s32));
        s32 = fmaf(b32, v, a32 * y3);
        // section 4 (lowpass)
        float y4 = fmaf(b40, y3, s41);
        s41 = fmaf(b41, y3, fmaf(a41, y4, s42));
        s42 = fmaf(b42, y3, a42 * y4);
        return y4;
    };

    // 4x8 register load ring + 32-reg output buffer. All indices static after unroll.
    float P0[8], P1[8], P2[8], P3[8];
    float Y[32];

    auto load8 = [&](float* d) {
#pragma unroll
        for (int j = 0; j < 8; ++j) d[j] = lq[j * C_LEN];  // dword + imm offsets off one addr
        lq += 8 * C_LEN;
    };
    auto warm8 = [&](const float* d) {
#pragma unroll
        for (int j = 0; j < 8; ++j) step(d[j]);            // outputs discarded; states advance
    };
    auto emit8 = [&](const float* d, float* y) {
#pragma unroll
        for (int j = 0; j < 8; ++j) y[j] = step(d[j]);     // to registers, no stores
    };
    auto fence = [&]() { __builtin_amdgcn_sched_barrier(0); };

    // Prologue: 32 samples in flight before the first dependent FMA.
    load8(P0); load8(P1); load8(P2); load8(P3);
    fence();

    // Warm: warm/32 rotations (0 or 2). {consume 8, reload 8}, fenced. Loads only.
    const int nrot = warm >> 5;
#pragma unroll 1
    for (int r = 0; r < nrot; ++r) {
        warm8(P0); load8(P0); fence();
        warm8(P1); load8(P1); fence();
        warm8(P2); load8(P2); fence();
        warm8(P3); load8(P3); fence();
    }

    // Emit half 1: consume [warm, warm+32) -> Y, reload [warm+32, warm+64).
    // Total loads = warm + CHUNK, ending exactly at t_out0 + CHUNK <= T: no OOB.
    emit8(P0, Y +  0); load8(P0); fence();
    emit8(P1, Y +  8); load8(P1); fence();
    emit8(P2, Y + 16); load8(P2); fence();
    emit8(P3, Y + 24); load8(P3); fence();

    // Store batch 1: 32 outputs. Only loads already issued (and consumed ~8 phases
    // later in half 2? none remain) sit behind these in the FIFO.
#pragma unroll
    for (int i = 0; i < 32; ++i)
        __builtin_nontemporal_store(Y[i], po + i * C_LEN);
    fence();

    // Emit half 2: consume [warm+32, warm+64) -> Y (reused; WAR resolves via expcnt).
    // No loads here -> zero store-load coupling.
    emit8(P0, Y +  0); fence();
    emit8(P1, Y +  8); fence();
    emit8(P2, Y + 16); fence();
    emit8(P3, Y + 24); fence();

    // Store batch 2.
#pragma unroll
    for (int i = 0; i < 32; ++i)
        __builtin_nontemporal_store(Y[i], po + (32 + i) * C_LEN);
}

extern "C" void kernel_launch(void* const* d_in, const int* in_sizes, int n_in,
                              void* d_out, int out_size, void* d_ws, size_t ws_size,
                              hipStream_t stream) {
    const float* x  = (const float*)d_in[0];
    const float* bp = (const float*)d_in[1];
    const float* lp = (const float*)d_in[2];
    float* out      = (float*)d_out;

    dim3 grid(T_LEN / CHUNK, B_LEN / 4);   // 256 x 4 = 1024 blocks -> 4 blocks/CU, 16 waves/CU
    dim3 block(256);                        // 4 waves: 4 batches x 64 channels
    iir_defer_kernel<<<grid, block, 0, stream>>>(x, bp, lp, out);
}